// Round 6
// baseline (496.321 us; speedup 1.0000x reference)
//
#include <hip/hip_runtime.h>
#include <hip/hip_bf16.h>
#include <stdint.h>

// Graph_Refine: N=8192, D=128, E=262144, P=4, eps=0.3. fp32 I/O.
// R20: TM=256 gram. R19's sparse experiment isolated the gemm: ~35us stores,
// ~115us loads/latency. Load traffic ~ (TM+TN)/(TM*TN): 256^2 tiles halve
// L2/L3 read traffic (532MB -> 277MB) and cut kt barrier-drain chains 4x.
// 256^2 was unreachable in prior pinned "tiles x3" (needs 1024 threads:
// acc=64 VGPR; at 512 thr it would be 128). Dense stores restored (measured
// strictly better than prefill+sparse). Structure: 16 waves 4x4, 64x64/wave,
// epA nt-stores + epB 4-pass LDS transpose (TLD=260 == 4 mod 32, proven
// conflict profile), inline ballot fixup from acc, per-tile edge buckets.
#define N_NODES 8192
#define DIM     128
#define KTOT    512
#define NEDGE   262144
#define EPS     0.3f
#define FIX_DELTA 0.0043f  // > provable bf16 dot bound 2^-8*Sum|ab| <= 0.0039
#define HASH_BITS 19
#define HASH_SLOTS (1u << HASH_BITS)
#define NTRI    528        // 32*33/2 upper-tri 256x256 tiles
#define TRI_CAP 768        // per-bucket capacity (avg ~495 off-diag, +11 sigma)
#define OCAP    131072     // bucket-overflow list capacity (normally 0 used)

typedef unsigned int u32;
typedef unsigned short u16;
typedef __attribute__((ext_vector_type(8))) short short8;
typedef __attribute__((ext_vector_type(4))) float float4v;
typedef __attribute__((ext_vector_type(4))) u32 u32x4;

// workspace layout (bytes)
#define OFF_YF  0u           // fp32 Y [8192][512] 16 MB
#define OFF_YB  16777216u    // bf16 Y  8 MB
#define OFF_CTR 25165824u    // counters: oc@0 (bucket-overflow count)
#define OFF_BC  25166080u    // bucket counts u32[528] (reserve 4KB)
#define OFF_HK  25170176u    // hash keys u32[2^19] 2 MB
#define OFF_HV  27267328u    // hash vals f32[2^19] 2 MB
#define OFF_OL  29364480u    // overflow list u32[131072] 512 KB
#define OFF_BL  29888768u    // bucket lists u32[528*768] ~1.6 MB
#define ZERO_VEC4 262416u    // (OFF_OL-OFF_CTR)/16 16B-chunks zeroed in prep_y

__device__ __forceinline__ u16 f2bf(float f) {  // RNE
    u32 b = __builtin_bit_cast(u32, f);
    b += 0x7fffu + ((b >> 16) & 1u);
    return (u16)(b >> 16);
}

// wave-cooperative exact fp32 dot of rows i,j of Y (all 64 lanes; result on all)
__device__ __forceinline__ float wave_dot(const float* __restrict__ yf,
                                          u32 i, u32 j, int lane) {
    const float4v* ri = (const float4v*)(yf + (size_t)i * KTOT);
    const float4v* rj = (const float4v*)(yf + (size_t)j * KTOT);
    float4v p = ri[lane] * rj[lane] + ri[64 + lane] * rj[64 + lane];
    float s = p.x + p.y + p.z + p.w;
    #pragma unroll
    for (int o = 32; o >= 1; o >>= 1) s += __shfl_xor(s, o, 64);
    return s;
}

// triangular index over 32x32 256-tiles
__device__ __forceinline__ u32 tri_of(u32 ti, u32 tj) {
    u32 bm = ti < tj ? ti : tj;
    u32 bn = ti < tj ? tj : ti;
    return bm * (65u - bm) / 2u + (bn - bm);
}

// K1: reweight + L2-normalize per perspective; Y fp32 + bf16 (0.5 folds mean over P).
// Blocks >= 2048 zero the counter+bucket+hash region.
__global__ void prep_y(const float* __restrict__ x, const float* __restrict__ wp,
                       float* __restrict__ yf, u16* __restrict__ yb,
                       u32x4* __restrict__ zbase) {
    if (blockIdx.x >= 2048) {                  // ws-zero
        u32x4 z = {0u, 0u, 0u, 0u};
        for (u32 idx = (blockIdx.x - 2048) * 256 + threadIdx.x; idx < ZERO_VEC4;
             idx += 512 * 256)
            zbase[idx] = z;
        return;
    }
    int node = blockIdx.x * 4 + (threadIdx.x >> 6);
    int lane = threadIdx.x & 63;
    float x0 = x[node * DIM + lane];
    float x1 = x[node * DIM + lane + 64];
    for (int p = 0; p < 4; ++p) {
        float v0 = x0 * wp[p * DIM + lane];
        float v1 = x1 * wp[p * DIM + lane + 64];
        float ss = v0 * v0 + v1 * v1;
        #pragma unroll
        for (int o = 1; o < 64; o <<= 1) ss += __shfl_xor(ss, o, 64);
        float scale = 0.5f / fmaxf(sqrtf(ss), 1e-12f);
        float y0 = v0 * scale, y1 = v1 * scale;
        int base = node * KTOT + p * DIM;
        yf[base + lane] = y0;       yf[base + lane + 64] = y1;
        yb[base + lane] = f2bf(y0); yb[base + lane + 64] = f2bf(y1);
    }
}

// K2: hash-aggregate duplicate edges + scatter unique cells into per-tile buckets
__global__ void edge_insert(const int* __restrict__ idx, const float* __restrict__ w,
                            u32* __restrict__ hkey, float* __restrict__ hval,
                            u32* __restrict__ bcnt, u32* __restrict__ blist,
                            u32* __restrict__ ocnt, u32* __restrict__ olist) {
    int e = blockIdx.x * 256 + threadIdx.x;
    u32 i = (u32)idx[e], j = (u32)idx[NEDGE + e];
    u32 cell = i * (u32)N_NODES + j;
    float wv = w[e];
    u32 key = cell + 1u;
    u32 h = (cell * 2654435761u) >> (32 - HASH_BITS);
    while (true) {
        u32 old = atomicCAS(&hkey[h], 0u, key);
        if (old == 0u) {                       // first claim: bucket this cell
            u32 tri = tri_of(i >> 8, j >> 8);
            u32 bi = atomicAdd(&bcnt[tri], 1u);
            if (bi < TRI_CAP) blist[tri * TRI_CAP + bi] = h;
            else { u32 g = atomicAdd(ocnt, 1u); if (g < OCAP) olist[g] = h; }
            atomicAdd(&hval[h], wv);
            break;
        }
        if (old == key) { atomicAdd(&hval[h], wv); break; }
        h = (h + 1u) & (HASH_SLOTS - 1u);
    }
}

// K3: sim = Yb*Yb^T, 256^2 tiles, upper-tri grid (33x16 = 528), 1024 thr / 16 waves.
// Wave grid 4x4, each wave 64x64 output (acc 4x4 frags = 64 VGPR).
#define TM  256
#define BK  64
#define TLD 260   // transpose stride (floats): == 4 mod 32 (proven profile), 16B mult

__global__ __launch_bounds__(1024)
void gemm_sim(const u16* __restrict__ yb, const float* __restrict__ yf,
              float* __restrict__ out,
              const u32* __restrict__ hkey, const float* __restrict__ hval,
              const u32* __restrict__ bcnt, const u32* __restrict__ blist,
              const u32* __restrict__ ocnt, const u32* __restrict__ olist) {
    // triangular decode over 32 tile-rows: rows r and 31-r pair to 33 tiles
    int r = blockIdx.y, c = blockIdx.x;
    int bm, bn;
    if (c < 32 - r) { bm = r;      bn = r + c; }
    else            { bm = 31 - r; bn = bm + (c - (32 - r)); }
    __shared__ __align__(16) char smem[64 * TLD * 4];   // 66560 B: As+Bs | tbuf
    u16* As = (u16*)smem;                      // [256][64] 32 KB
    u16* Bs = As + TM * BK;                    // [256][64] 32 KB
    float* tbuf = (float*)smem;                // [64][TLD] after K-loop
    int tid = threadIdx.x;
    int lane = tid & 63, wid = tid >> 6;       // 16 waves
    int wm = wid >> 2, wn = wid & 3;           // 4x4: rows [wm*64,+64) x cols [wn*64,+64)

    float4v acc[4][4] = {};
    const u16* arow = yb + (size_t)(bm * TM) * KTOT;
    const u16* brow = yb + (size_t)(bn * TM) * KTOT;

    for (int kt = 0; kt < KTOT / BK; ++kt) {
        __syncthreads();
        #pragma unroll
        for (int q = 0; q < 2; ++q) {
            int cc = q * 1024 + wid * 64 + lane; // chunk id 0..2047 (16B units)
            int row = cc >> 3;
            int kg = (cc & 7) ^ (row & 7);       // source-side XOR swizzle
            __builtin_amdgcn_global_load_lds(
                (const __attribute__((address_space(1))) void*)(const void*)(arow + (size_t)row * KTOT + kt * BK + kg * 8),
                (__attribute__((address_space(3))) void*)(void*)(As + (q * 1024 + wid * 64) * 8),
                16, 0, 0);
            __builtin_amdgcn_global_load_lds(
                (const __attribute__((address_space(1))) void*)(const void*)(brow + (size_t)row * KTOT + kt * BK + kg * 8),
                (__attribute__((address_space(3))) void*)(void*)(Bs + (q * 1024 + wid * 64) * 8),
                16, 0, 0);
        }
        __syncthreads();
        #pragma unroll
        for (int kk = 0; kk < 2; ++kk) {
            short8 af[4], bfr[4];
            int kg2 = kk * 4 + (lane >> 4);
            int mrow = wm * 64 + (lane & 15);
            int ncol = wn * 64 + (lane & 15);
            #pragma unroll
            for (int i = 0; i < 4; ++i) {
                int ra = mrow + i * 16;
                af[i] = *(const short8*)&As[ra * BK + ((kg2 ^ (ra & 7)) * 8)];
            }
            #pragma unroll
            for (int j = 0; j < 4; ++j) {
                int rb = ncol + j * 16;
                bfr[j] = *(const short8*)&Bs[rb * BK + ((kg2 ^ (rb & 7)) * 8)];
            }
            #pragma unroll
            for (int i = 0; i < 4; ++i)
                #pragma unroll
                for (int j = 0; j < 4; ++j)
                    acc[i][j] = __builtin_amdgcn_mfma_f32_16x16x32_bf16(
                        af[i], bfr[j], acc[i][j], 0, 0, 0);
        }
    }

    // epilogue A: dense thresholded direct stores (nt).
    // C/D: col=lane&15, row=quad*4+rr [m89/m91]
    int quad = lane >> 4, lcol = lane & 15;
    #pragma unroll
    for (int i = 0; i < 4; ++i)
        #pragma unroll
        for (int j = 0; j < 4; ++j) {
            int gr0 = bm * TM + wm * 64 + i * 16 + quad * 4;
            int gc  = bn * TM + wn * 64 + j * 16 + lcol;
            #pragma unroll
            for (int rr = 0; rr < 4; ++rr) {
                float s = acc[i][j][rr];
                __builtin_nontemporal_store(s > EPS ? s : 0.f,
                                            &out[(size_t)(gr0 + rr) * N_NODES + gc]);
            }
        }

    // epilogue B: mirrored tile via LDS transpose, four 64-col half-passes
    #pragma unroll
    for (int h = 0; h < 4; ++h) {
        __syncthreads();
        if (wn == h) {                          // 4 waves write their 64x64 accs
            #pragma unroll
            for (int i = 0; i < 4; ++i) {
                int Lr = wm * 64 + i * 16 + quad * 4;
                #pragma unroll
                for (int j = 0; j < 4; ++j) {
                    int Lc = j * 16 + lcol;
                    *(float4v*)&tbuf[Lc * TLD + Lr] = acc[i][j];
                }
            }
        }
        __syncthreads();
        #pragma unroll
        for (int v = 0; v < 4; ++v) {
            int chunk = v * 1024 + tid;         // 4096 float4 = 64x256 floats
            int row = chunk >> 6, c4 = chunk & 63;
            float4v t = *(const float4v*)&tbuf[row * TLD + c4 * 4];
            float4v o;
            #pragma unroll
            for (int rr = 0; rr < 4; ++rr) o[rr] = t[rr] > EPS ? t[rr] : 0.f;
            __builtin_nontemporal_store(o,
                (float4v*)&out[(size_t)(bn * TM + h * 64 + row) * N_NODES + bm * TM + c4 * 4]);
        }
    }

    __syncthreads();   // drain epilogue stores before fixup overwrites

    // inline exact fixup: per-wave ballot drain directly from acc registers.
    #pragma unroll
    for (int i = 0; i < 4; ++i)
        #pragma unroll
        for (int j = 0; j < 4; ++j)
            #pragma unroll
            for (int rr = 0; rr < 4; ++rr) {
                float s = acc[i][j][rr];
                unsigned long long m = __ballot(fabsf(s - EPS) < FIX_DELTA);
                while (m) {
                    int src = __builtin_ctzll(m);
                    m &= m - 1;
                    u32 fi = (u32)(bm * TM + wm * 64 + i * 16 + (src >> 4) * 4 + rr);
                    u32 fj = (u32)(bn * TM + wn * 64 + j * 16 + (src & 15));
                    float sx = wave_dot(yf, fi, fj, lane);
                    if (lane == 0) {
                        float v = sx > EPS ? sx : 0.f;
                        out[(size_t)fi * N_NODES + fj] = v;
                        out[(size_t)fj * N_NODES + fi] = v;
                    }
                }
            }

    __syncthreads();   // fixup writes visible before edge reads

    // edge pass: this tile-pair's bucket. sg reads are post-fixup by construction.
    u32 tri = tri_of((u32)bm, (u32)bn);
    u32 cnt = bcnt[tri]; if (cnt > TRI_CAP) cnt = TRI_CAP;
    {
        u32 t = (u32)tid;
        bool valid = t < cnt;
        u32 cell = 0; float a = 0.f, sg = 0.f; bool hardc = false;
        if (valid) {
            u32 h = blist[tri * TRI_CAP + t];
            cell = hkey[h] - 1u;
            a = hval[h];
            sg = out[cell];
            hardc = (a > 1.0f) ||
                    (fabsf(sg - EPS) < FIX_DELTA + 1e-6f) ||
                    (sg > 0.f && fabsf(sg * a - EPS) < FIX_DELTA * a + 1e-6f) ||
                    (sg == 0.f && a > 0.9855f);  // provable EPS/(EPS+FIX_DELTA)=0.98587
            if (!hardc && sg > 0.f)
                out[cell] = sg + ((sg * a > EPS) ? a : 0.f);
        }
        unsigned long long m = __ballot(hardc);
        while (m) {
            int src = __builtin_ctzll(m);
            m &= m - 1;
            u32 cB = __shfl(cell, src, 64);
            float aB = __shfl(a, src, 64);
            float sx = wave_dot(yf, cB >> 13, cB & 8191u, lane);
            if (lane == 0) {
                float v = sx > EPS ? sx : 0.f;
                if (sx * aB > EPS) v += aB;
                out[cB] = v;
            }
        }
    }

    // bucket-overflow drain (normally empty): scan shared list, filter own tri.
    u32 ovn = *ocnt; if (ovn > OCAP) ovn = OCAP;
    for (u32 base = 0; base < ovn; base += 1024) {
        u32 t = base + (u32)tid;
        bool valid = t < ovn;
        u32 cell = 0; float a = 0.f, sg = 0.f; bool hardc = false;
        if (valid) {
            u32 h = olist[t];
            cell = hkey[h] - 1u;
            u32 ii = cell >> 13, jj = cell & 8191u;
            if (tri_of(ii >> 8, jj >> 8) == tri) {
                a = hval[h];
                sg = out[cell];
                hardc = (a > 1.0f) ||
                        (fabsf(sg - EPS) < FIX_DELTA + 1e-6f) ||
                        (sg > 0.f && fabsf(sg * a - EPS) < FIX_DELTA * a + 1e-6f) ||
                        (sg == 0.f && a > 0.9855f);
                if (!hardc && sg > 0.f)
                    out[cell] = sg + ((sg * a > EPS) ? a : 0.f);
            }
        }
        unsigned long long m = __ballot(hardc);
        while (m) {
            int src = __builtin_ctzll(m);
            m &= m - 1;
            u32 cB = __shfl(cell, src, 64);
            float aB = __shfl(a, src, 64);
            float sx = wave_dot(yf, cB >> 13, cB & 8191u, lane);
            if (lane == 0) {
                float v = sx > EPS ? sx : 0.f;
                if (sx * aB > EPS) v += aB;
                out[cB] = v;
            }
        }
    }
}

extern "C" void kernel_launch(void* const* d_in, const int* in_sizes, int n_in,
                              void* d_out, int out_size, void* d_ws, size_t ws_size,
                              hipStream_t stream) {
    const float* x  = (const float*)d_in[0];
    const int*   oi = (const int*)d_in[1];
    const float* ow = (const float*)d_in[2];
    const float* wp = (const float*)d_in[3];
    float* out = (float*)d_out;
    char* ws = (char*)d_ws;
    float* yf = (float*)(ws + OFF_YF);
    u16*   yb = (u16*)(ws + OFF_YB);
    u32*   oc = (u32*)(ws + OFF_CTR);
    u32*   bc = (u32*)(ws + OFF_BC);
    u32*   hk = (u32*)(ws + OFF_HK);
    float* hv = (float*)(ws + OFF_HV);
    u32*   ol = (u32*)(ws + OFF_OL);
    u32*   bl = (u32*)(ws + OFF_BL);

    prep_y<<<2560, 256, 0, stream>>>(x, wp, yf, yb, (u32x4*)(ws + OFF_CTR));
    edge_insert<<<NEDGE / 256, 256, 0, stream>>>(oi, ow, hk, hv, bc, bl, oc, ol);
    gemm_sim<<<dim3(33, 16), 1024, 0, stream>>>(yb, yf, out, hk, hv, bc, bl, oc, ol);
}

// Round 7
// 422.960 us; speedup vs baseline: 1.1734x; 1.1734x over previous
//
#include <hip/hip_runtime.h>
#include <hip/hip_bf16.h>
#include <stdint.h>

// Graph_Refine: N=8192, D=128, E=262144, P=4, eps=0.3. fp32 I/O.
// R21 = R16 verbatim (measured best: 425.9us). Final configuration.
// Session ledger: 238us harness poison fills (untouchable, 72-74% HBM peak) +
// ~150us gemm (pinned across 14 variants; R19 isolated it: ~35us stores /
// ~115us load path; R20 proved occupancy > traffic: 256^2 tile halved loads
// but collapsed to 1 block/CU, +70us) + ~38us tail (R17 proved restructure-
// neutral). R16's wins on the path here: inline knife-edge fixup in gemm
// epilogue (ballot from acc-adjacent s_list), in-wave hard-edge resolution
// (K5 deleted), exact triangular grid, tightened sg==0 bound 0.9855.
#define N_NODES 8192
#define DIM     128
#define KTOT    512
#define NEDGE   262144
#define EPS     0.3f
#define FIX_DELTA 0.0043f  // > provable bf16 dot bound 2^-8*Sum|ab| <= 0.0039
#define FIX_CAP (1u << 19)
#define LCAP    512
#define HASH_BITS 19
#define HASH_SLOTS (1u << HASH_BITS)

typedef unsigned int u32;
typedef unsigned short u16;
typedef __attribute__((ext_vector_type(8))) short short8;
typedef __attribute__((ext_vector_type(4))) float float4v;

// workspace layout (bytes)
#define OFF_YF  0u           // fp32 Y [8192][512] 16 MB
#define OFF_YB  16777216u    // bf16 Y  8 MB
#define OFF_CTR 25165824u    // counters: fc@0, uc@4
#define OFF_HK  25166080u    // hash keys u32[2^19] 2 MB
#define OFF_HV  27263232u    // hash vals f32[2^19] 2 MB
#define OFF_FL  29360384u    // fixup overflow list u32 2 MB (normally empty)
#define OFF_UL  31457536u    // unique list u32 1 MB
#define ZERO_VEC4 262160u    // (OFF_FL-OFF_CTR)/16 uint4s zeroed in prep_y

__device__ __forceinline__ u16 f2bf(float f) {  // RNE
    u32 b = __builtin_bit_cast(u32, f);
    b += 0x7fffu + ((b >> 16) & 1u);
    return (u16)(b >> 16);
}

// wave-cooperative exact fp32 dot of rows i,j of Y (all 64 lanes; result on all)
__device__ __forceinline__ float wave_dot(const float* __restrict__ yf,
                                          u32 i, u32 j, int lane) {
    const float4v* ri = (const float4v*)(yf + (size_t)i * KTOT);
    const float4v* rj = (const float4v*)(yf + (size_t)j * KTOT);
    float4v p = ri[lane] * rj[lane] + ri[64 + lane] * rj[64 + lane];
    float s = p.x + p.y + p.z + p.w;
    #pragma unroll
    for (int o = 32; o >= 1; o >>= 1) s += __shfl_xor(s, o, 64);
    return s;
}

__device__ __forceinline__ bool is_edge(const u32* __restrict__ hkey, u32 cell) {
    u32 h = (cell * 2654435761u) >> (32 - HASH_BITS);
    while (true) {
        u32 k = hkey[h];
        if (k == 0u) return false;
        if (k == cell + 1u) return true;
        h = (h + 1u) & (HASH_SLOTS - 1u);
    }
}

// K1: reweight + L2-normalize per perspective; Y fp32 + bf16 (0.5 folds mean over P).
// Blocks >= 2048 zero the counter+hash region (replaces hipMemsetAsync).
__global__ void prep_y(const float* __restrict__ x, const float* __restrict__ wp,
                       float* __restrict__ yf, u16* __restrict__ yb,
                       uint4* __restrict__ zbase) {
    if (blockIdx.x >= 2048) {
        for (u32 idx = (blockIdx.x - 2048) * 256 + threadIdx.x; idx < ZERO_VEC4;
             idx += 512 * 256)
            zbase[idx] = make_uint4(0, 0, 0, 0);
        return;
    }
    int node = blockIdx.x * 4 + (threadIdx.x >> 6);
    int lane = threadIdx.x & 63;
    float x0 = x[node * DIM + lane];
    float x1 = x[node * DIM + lane + 64];
    for (int p = 0; p < 4; ++p) {
        float v0 = x0 * wp[p * DIM + lane];
        float v1 = x1 * wp[p * DIM + lane + 64];
        float ss = v0 * v0 + v1 * v1;
        #pragma unroll
        for (int o = 1; o < 64; o <<= 1) ss += __shfl_xor(ss, o, 64);
        float scale = 0.5f / fmaxf(sqrtf(ss), 1e-12f);
        float y0 = v0 * scale, y1 = v1 * scale;
        int base = node * KTOT + p * DIM;
        yf[base + lane] = y0;       yf[base + lane + 64] = y1;
        yb[base + lane] = f2bf(y0); yb[base + lane + 64] = f2bf(y1);
    }
}

// K2: hash-aggregate duplicate edges + compact unique-slot list
__global__ void edge_insert(const int* __restrict__ idx, const float* __restrict__ w,
                            u32* __restrict__ hkey, float* __restrict__ hval,
                            u32* __restrict__ ucnt, u32* __restrict__ ulist) {
    int e = blockIdx.x * 256 + threadIdx.x;
    u32 cell = (u32)(idx[e] * N_NODES + idx[NEDGE + e]);
    float wv = w[e];
    u32 key = cell + 1u;
    u32 h = (cell * 2654435761u) >> (32 - HASH_BITS);
    while (true) {
        u32 old = atomicCAS(&hkey[h], 0u, key);
        if (old == 0u) { ulist[atomicAdd(ucnt, 1u)] = h; atomicAdd(&hval[h], wv); break; }
        if (old == key) { atomicAdd(&hval[h], wv); break; }
        h = (h + 1u) & (HASH_SLOTS - 1u);
    }
}

// K3: sim = Yb*Yb^T, exact upper-tri grid (65x32 = 2080 tiles), 512 thr / 8 waves.
// Inline exact fixup of this block's knife-edge cells at the end (wave dots).
#define TM  128
#define BK  64
#define TLD 132   // transpose stride (floats): conflict-free at b128, 16B aligned

__global__ __launch_bounds__(512)
void gemm_sim(const u16* __restrict__ yb, const float* __restrict__ yf,
              float* __restrict__ out, u32* __restrict__ fcnt, u32* __restrict__ flst) {
    // triangular decode: rows r and 63-r pair to 65 tiles
    int r = blockIdx.y, c = blockIdx.x;
    int bm, bn;
    if (c < 64 - r) { bm = r;      bn = r + c; }
    else            { bm = 63 - r; bn = bm + (c - (64 - r)); }
    __shared__ __align__(16) char smem[64 * TLD * 4];   // 33792 B: As+Bs | tbuf
    u16* As = (u16*)smem;
    u16* Bs = As + TM * BK;
    float* tbuf = (float*)smem;                // used only after K-loop
    __shared__ u32 s_cnt;
    __shared__ u32 s_list[LCAP];
    int tid = threadIdx.x;
    int lane = tid & 63, wid = tid >> 6;       // 8 waves
    int wm = wid >> 1, wn = wid & 1;           // 4x2: rows [wm*32,+32) x cols [wn*64,+64)
    if (tid == 0) s_cnt = 0;

    float4v acc[2][4] = {};
    const u16* arow = yb + (size_t)(bm * TM) * KTOT;
    const u16* brow = yb + (size_t)(bn * TM) * KTOT;

    for (int kt = 0; kt < KTOT / BK; ++kt) {
        __syncthreads();
        #pragma unroll
        for (int q = 0; q < 2; ++q) {
            int cc = q * 512 + wid * 64 + lane; // chunk id 0..1023 (16B units)
            int row = cc >> 3;
            int kg = (cc & 7) ^ (row & 7);      // source-side XOR swizzle
            __builtin_amdgcn_global_load_lds(
                (const __attribute__((address_space(1))) void*)(const void*)(arow + (size_t)row * KTOT + kt * BK + kg * 8),
                (__attribute__((address_space(3))) void*)(void*)(As + (q * 512 + wid * 64) * 8),
                16, 0, 0);
            __builtin_amdgcn_global_load_lds(
                (const __attribute__((address_space(1))) void*)(const void*)(brow + (size_t)row * KTOT + kt * BK + kg * 8),
                (__attribute__((address_space(3))) void*)(void*)(Bs + (q * 512 + wid * 64) * 8),
                16, 0, 0);
        }
        __syncthreads();
        #pragma unroll
        for (int kk = 0; kk < 2; ++kk) {
            short8 af[2], bfr[4];
            int kg2 = kk * 4 + (lane >> 4);
            int mrow = wm * 32 + (lane & 15);
            int ncol = wn * 64 + (lane & 15);
            #pragma unroll
            for (int i = 0; i < 2; ++i) {
                int ra = mrow + i * 16;
                af[i] = *(const short8*)&As[ra * BK + ((kg2 ^ (ra & 7)) * 8)];
            }
            #pragma unroll
            for (int j = 0; j < 4; ++j) {
                int rb = ncol + j * 16;
                bfr[j] = *(const short8*)&Bs[rb * BK + ((kg2 ^ (rb & 7)) * 8)];
            }
            #pragma unroll
            for (int i = 0; i < 2; ++i)
                #pragma unroll
                for (int j = 0; j < 4; ++j)
                    acc[i][j] = __builtin_amdgcn_mfma_f32_16x16x32_bf16(
                        af[i], bfr[j], acc[i][j], 0, 0, 0);
        }
    }

    // epilogue A: dense thresholded direct stores (nt) + knife-edge flags.
    // C/D: col=lane&15, row=quad*4+r [m89/m91]
    int quad = lane >> 4, lcol = lane & 15;
    #pragma unroll
    for (int i = 0; i < 2; ++i)
        #pragma unroll
        for (int j = 0; j < 4; ++j) {
            int gr0 = bm * TM + wm * 32 + i * 16 + quad * 4;
            int gc  = bn * TM + wn * 64 + j * 16 + lcol;
            #pragma unroll
            for (int rr = 0; rr < 4; ++rr) {
                float s = acc[i][j][rr];
                __builtin_nontemporal_store(s > EPS ? s : 0.f,
                                            &out[(size_t)(gr0 + rr) * N_NODES + gc]);
                if (fabsf(s - EPS) < FIX_DELTA) {
                    u32 cell = (u32)((gr0 + rr) * N_NODES + gc);
                    u32 li = atomicAdd(&s_cnt, 1u);
                    if (li < LCAP) s_list[li] = cell;
                    else { u32 g = atomicAdd(fcnt, 1u); if (g < FIX_CAP) flst[g] = cell; }
                }
            }
        }

    // epilogue B: mirrored tile via LDS transpose, two half-passes (waves wn==h write)
    #pragma unroll
    for (int h = 0; h < 2; ++h) {
        __syncthreads();
        if (wn == h) {
            #pragma unroll
            for (int i = 0; i < 2; ++i) {
                int Lr = wm * 32 + i * 16 + quad * 4;
                #pragma unroll
                for (int j = 0; j < 4; ++j) {
                    int Lc = j * 16 + lcol;
                    *(float4v*)&tbuf[Lc * TLD + Lr] = acc[i][j];
                }
            }
        }
        __syncthreads();
        #pragma unroll
        for (int v = 0; v < 4; ++v) {
            int chunk = v * 512 + tid;          // 2048 float4 = 64x128 floats
            int row = chunk >> 5, c4 = chunk & 31;
            float4v t = *(const float4v*)&tbuf[row * TLD + c4 * 4];
            float4v o;
            #pragma unroll
            for (int rr = 0; rr < 4; ++rr) o[rr] = t[rr] > EPS ? t[rr] : 0.f;
            __builtin_nontemporal_store(o,
                (float4v*)&out[(size_t)(bn * TM + h * 64 + row) * N_NODES + bm * TM + c4 * 4]);
        }
    }

    // inline exact fixup: block-owned knife-edge cells, one wave-dot each.
    // Writes both orientations (mirror was stored by epilogue B of this block;
    // barrier drains those stores first).
    __syncthreads();
    u32 cnt = s_cnt < LCAP ? s_cnt : LCAP;
    for (u32 t = wid; t < cnt; t += 8) {
        u32 cell = s_list[t];
        u32 ii = cell >> 13, jj = cell & 8191u;
        float s = wave_dot(yf, ii, jj, lane);
        if (lane == 0) {
            float v = s > EPS ? s : 0.f;
            out[(size_t)ii * N_NODES + jj] = v;
            out[(size_t)jj * N_NODES + ii] = v;
        }
    }
}

// K4 (fused, final): blocks [0,1024) = edges: one unique cell per thread; sg reads
// are post-fixup (gemm fixed knife-edge cells inline). Easy cells write directly;
// hard cells (a>1, knife-edge sim, knife-edge product, or sg==0 && a>0.9855 —
// provable bound EPS/(EPS+FIX_DELTA)=0.98587) are resolved IN-WAVE via ballot +
// whole-wave exact dot. Blocks [1024,1088) = fixup-overflow drain (normally empty);
// skips orientations owned by the edge path via hash lookup.
__global__ void fix_and_edges(const float* __restrict__ yf,
                              const u32* __restrict__ fcnt, const u32* __restrict__ flst,
                              const u32* __restrict__ hkey, const float* __restrict__ hval,
                              const u32* __restrict__ ucnt, const u32* __restrict__ ulist,
                              float* __restrict__ out) {
    int lane = threadIdx.x & 63;
    if (blockIdx.x < 1024) {                    // ---- edge part: 262144 threads
        u32 count = *ucnt;
        u32 t = blockIdx.x * 256 + threadIdx.x;
        bool valid = t < count;
        u32 cell = 0; float a = 0.f, sg = 0.f; bool hard = false;
        if (valid) {
            u32 h = ulist[t];
            cell = hkey[h] - 1u;
            a = hval[h];
            sg = out[cell];
            hard = (a > 1.0f) ||
                   (fabsf(sg - EPS) < FIX_DELTA + 1e-6f) ||
                   (sg > 0.f && fabsf(sg * a - EPS) < FIX_DELTA * a + 1e-6f) ||
                   (sg == 0.f && a > 0.9855f);
            if (!hard && sg > 0.f)
                out[cell] = sg + ((sg * a > EPS) ? a : 0.f);
        }
        unsigned long long m = __ballot(hard);
        while (m) {
            int src = __builtin_ctzll(m);
            m &= m - 1;
            u32 cB = __shfl(cell, src, 64);
            float aB = __shfl(a, src, 64);
            float s = wave_dot(yf, cB >> 13, cB & 8191u, lane);
            if (lane == 0) {
                float v = s > EPS ? s : 0.f;
                if (s * aB > EPS) v += aB;
                out[cB] = v;
            }
        }
    } else {                                    // ---- overflow drain (dead on this data)
        u32 count = *fcnt; if (count > FIX_CAP) count = FIX_CAP;
        u32 wv = (blockIdx.x - 1024) * 4 + (threadIdx.x >> 6);
        for (u32 t = wv; t < count; t += 64 * 4) {
            u32 cell = flst[t];
            u32 ii = cell >> 13, jj = cell & 8191u;
            float s = wave_dot(yf, ii, jj, lane);
            float v = s > EPS ? s : 0.f;
            u32 mir = jj * (u32)N_NODES + ii;
            if (lane == 0 && !is_edge(hkey, cell)) out[(size_t)ii * N_NODES + jj] = v;
            if (lane == 1 && !is_edge(hkey, mir))  out[(size_t)jj * N_NODES + ii] = v;
        }
    }
}

extern "C" void kernel_launch(void* const* d_in, const int* in_sizes, int n_in,
                              void* d_out, int out_size, void* d_ws, size_t ws_size,
                              hipStream_t stream) {
    const float* x  = (const float*)d_in[0];
    const int*   oi = (const int*)d_in[1];
    const float* ow = (const float*)d_in[2];
    const float* wp = (const float*)d_in[3];
    float* out = (float*)d_out;
    char* ws = (char*)d_ws;
    float* yf = (float*)(ws + OFF_YF);
    u16*   yb = (u16*)(ws + OFF_YB);
    u32*   fc = (u32*)(ws + OFF_CTR);
    u32*   uc = (u32*)(ws + OFF_CTR + 4);
    u32*   hk = (u32*)(ws + OFF_HK);
    float* hv = (float*)(ws + OFF_HV);
    u32*   fl = (u32*)(ws + OFF_FL);
    u32*   ul = (u32*)(ws + OFF_UL);

    prep_y<<<2560, 256, 0, stream>>>(x, wp, yf, yb, (uint4*)(ws + OFF_CTR));
    edge_insert<<<NEDGE / 256, 256, 0, stream>>>(oi, ow, hk, hv, uc, ul);
    gemm_sim<<<dim3(65, 32), 512, 0, stream>>>(yb, yf, out, fc, fl);
    fix_and_edges<<<1088, 256, 0, stream>>>(yf, fc, fl, hk, hv, uc, ul, out);
}